// Round 11
// baseline (455.340 us; speedup 1.0000x reference)
//
#include <hip/hip_runtime.h>
#include <hip/hip_bf16.h>
#include <stdint.h>

typedef unsigned short u16;
typedef __attribute__((ext_vector_type(8))) short short8;
typedef __attribute__((ext_vector_type(8))) u16   u16x8;
typedef __attribute__((ext_vector_type(4))) u16   u16x4;
typedef __attribute__((ext_vector_type(4))) float f32x4;

#define B_DIM  8192
#define G_DIM  20000
#define H1_DIM 512
#define H2_DIM 256
#define P_DIM  128
#define A_DIM  64
#define SPLITK 8
#define NKT_ALL 625   // 20000 / 32

union Frag { short8 s; u16x8 u; };

__device__ __forceinline__ u16 f2b(float f) {
  union { __hip_bfloat16 b; u16 u; } c;
  c.b = __float2bfloat16(f);
  return c.u;
}

__device__ __forceinline__ void gld16(const void* g, void* l) {
  __builtin_amdgcn_global_load_lds(
      (const __attribute__((address_space(1))) void*)g,
      (__attribute__((address_space(3))) void*)l, 16, 0, 0);
}

// ---------------- prep: f32 -> bf16 convert (vectorized) ----------------
__global__ void k_convert(const float* __restrict__ src, u16* __restrict__ dst, int n4) {
  int i = blockIdx.x * 256 + threadIdx.x;
  if (i >= n4) return;
  f32x4 v = ((const f32x4*)src)[i];
  u16x4 o;
  o[0] = f2b(v[0]); o[1] = f2b(v[1]);
  o[2] = f2b(v[2]); o[3] = f2b(v[3]);
  ((u16x4*)dst)[i] = o;
}

// ---------------- prep: W1 f32 -> MFMA-fragment-linear bf16 ----------------
// chunk ot = (rowblk*625 + kt)*64 + lane  ->  W1[rowblk*16 + (lane&15)]
//                                             [kt*32 + (lane>>4)*8 + 0..7]
__global__ void k_convert_w1frag(const float* __restrict__ W1, u16* __restrict__ W1f) {
  int ot = blockIdx.x * 256 + threadIdx.x;       // 0 .. 1,279,999
  if (ot >= (H1_DIM / 16) * NKT_ALL * 64) return;
  int rowblk = ot / (NKT_ALL * 64);
  int rem    = ot - rowblk * (NKT_ALL * 64);
  int kt     = rem >> 6;
  int lane   = rem & 63;
  int row = rowblk * 16 + (lane & 15);
  int col = kt * 32 + (lane >> 4) * 8;
  const float* src = W1 + (size_t)row * G_DIM + col;
  f32x4 v0 = *(const f32x4*)src;
  f32x4 v1 = *(const f32x4*)(src + 4);
  u16x8 o;
#pragma unroll
  for (int i = 0; i < 4; ++i) { o[i] = f2b(v0[i]); o[i + 4] = f2b(v1[i]); }
  ((u16x8*)W1f)[ot] = o;
}

// ---------------- prep: W3 f32 -> MFMA-fragment-linear bf16 ----------------
// chunk ot = ((p*4 + nf)*8 + kt)*64 + lane
//   element j = W3[p][h = kt*32 + (lane>>4)*8 + j][a = nf*16 + (lane&15)]
// -> lane-exact B operand for mfma_16x16x32 (N = a-dim, K = h-dim)
__global__ void k_convert_w3frag(const float* __restrict__ W3, u16* __restrict__ W3f) {
  int ot = blockIdx.x * 256 + threadIdx.x;       // 0 .. 262,143
  if (ot >= P_DIM * 4 * 8 * 64) return;
  int p    = ot >> 11;
  int rem  = ot & 2047;
  int nf   = rem >> 9;
  int kt   = (rem >> 6) & 7;
  int lane = ot & 63;
  int a  = nf * 16 + (lane & 15);
  int h0 = kt * 32 + (lane >> 4) * 8;
  u16x8 o;
#pragma unroll
  for (int j = 0; j < 8; ++j)
    o[j] = f2b(W3[((size_t)p * H2_DIM + h0 + j) * A_DIM + a]);
  ((u16x8*)W3f)[ot] = o;
}

// ---------------- K1: layer-1 GEMM (unchanged from R10) ----------------
__global__ __launch_bounds__(512, 4)
void k_gemm1(const float* __restrict__ X, const u16* __restrict__ W1f,
             float* __restrict__ partial) {
  const int ks = blockIdx.x & 7;
  const int m0 = (blockIdx.x >> 3) * 64;
  const int kt_begin = (ks == 0) ? 0 : (ks * 78 + 1);   // {79, 78x7} of 625
  const int nkt = (ks == 0) ? 79 : 78;

  const int tid  = threadIdx.x;
  const int lane = tid & 63;
  const int w    = tid >> 6;
  const int c15 = lane & 15, j4 = lane >> 4;
  const int w4 = w * 4;

  __shared__ u16 lsA[2][64 * 64];   // 8 KB/buf; phys slot = g ^ (row&7)

  const int aRow = tid >> 3;
  const int aG   = tid & 7;
  const int aPhysU16 = aRow * 64 + ((aG ^ (aRow & 7)) * 8);
  const float* aSrc0 = X + (size_t)(m0 + aRow) * G_DIM + aG * 8;

  f32x4 zero = {0.f, 0.f, 0.f, 0.f};
  f32x4 acc[4][4];
#pragma unroll
  for (int m = 0; m < 4; ++m)
#pragma unroll
    for (int n = 0; n < 4; ++n) acc[m][n] = zero;

  auto loadB = [&](int kt, Frag* br) {
#pragma unroll
    for (int n = 0; n < 4; ++n)
      br[n].s = *(const short8*)(W1f + ((size_t)((w4 + n) * NKT_ALL + kt) * 64 + lane) * 8);
  };
  f32x4 ar0, ar1;
  auto loadA = [&](int kt) {
    const float* src = aSrc0 + (size_t)kt * 32;
    ar0 = *(const f32x4*)src;
    ar1 = *(const f32x4*)(src + 4);
  };
  auto writeA = [&](int buf) {
    u16x8 o;
#pragma unroll
    for (int i = 0; i < 4; ++i) { o[i] = f2b(ar0[i]); o[i + 4] = f2b(ar1[i]); }
    *(u16x8*)&lsA[buf][aPhysU16] = o;
  };
  auto readAfr = [&](int buf, int half, Frag* afr) {
#pragma unroll
    for (int m = 0; m < 4; ++m) {
      int row = m * 16 + c15;
      int g = half * 4 + j4;
      int phys = g ^ (row & 7);
      afr[m].s = *(const short8*)&lsA[buf][row * 64 + phys * 8];
    }
  };

  Frag bfrE[4], bfrO[4];

  loadA(kt_begin);
  loadB(kt_begin, bfrE);
  writeA(0);
  asm volatile("s_waitcnt lgkmcnt(0)" ::: "memory");
  __builtin_amdgcn_s_barrier();
  __builtin_amdgcn_sched_barrier(0);

  const int nsuper = 39;
  for (int T = 0; T < nsuper; ++T) {
    const int buf = T & 1;
    const int kt0 = kt_begin + 2 * T;
    const int ktN = 2 * (T + 1);
    const int ktNext = kt_begin + ((ktN < nkt) ? ktN : (nkt - 1));

    loadA(ktNext);
    loadB(kt0 + 1, bfrO);

    Frag afr[4];
    readAfr(buf, 0, afr);
#pragma unroll
    for (int m = 0; m < 4; ++m)
#pragma unroll
      for (int n = 0; n < 4; ++n)
        acc[m][n] = __builtin_amdgcn_mfma_f32_16x16x32_bf16(afr[m].s, bfrE[n].s, acc[m][n], 0, 0, 0);

    loadB(ktNext, bfrE);

    readAfr(buf, 1, afr);
#pragma unroll
    for (int m = 0; m < 4; ++m)
#pragma unroll
      for (int n = 0; n < 4; ++n)
        acc[m][n] = __builtin_amdgcn_mfma_f32_16x16x32_bf16(afr[m].s, bfrO[n].s, acc[m][n], 0, 0, 0);

    writeA(buf ^ 1);
    asm volatile("s_waitcnt lgkmcnt(0)" ::: "memory");
    __builtin_amdgcn_s_barrier();
    __builtin_amdgcn_sched_barrier(0);
  }

  if (nkt == 79) {
    Frag afr[4];
    readAfr(1, 0, afr);
#pragma unroll
    for (int m = 0; m < 4; ++m)
#pragma unroll
      for (int n = 0; n < 4; ++n)
        acc[m][n] = __builtin_amdgcn_mfma_f32_16x16x32_bf16(afr[m].s, bfrE[n].s, acc[m][n], 0, 0, 0);
  }

  float* outp = partial + ((size_t)ks * B_DIM + m0) * H1_DIM;
#pragma unroll
  for (int m = 0; m < 4; ++m)
#pragma unroll
    for (int n = 0; n < 4; ++n)
#pragma unroll
      for (int r = 0; r < 4; ++r) {
        int row = m * 16 + j4 * 4 + r;
        int col = w * 64 + n * 16 + c15;
        outp[(size_t)row * H1_DIM + col] = acc[m][n][r];
      }
}

// ---------------- K1b: sum 8 partials + bias + relu -> h1 bf16 ----------------
__global__ void k_reduce1(const float* __restrict__ partial, const float* __restrict__ b1,
                          u16* __restrict__ h1b) {
  const int n4 = B_DIM * H1_DIM / 4;
  int i = blockIdx.x * 256 + threadIdx.x;
  if (i >= n4) return;
  f32x4 s = ((const f32x4*)partial)[i];
#pragma unroll
  for (int k = 1; k < SPLITK; ++k) {
    f32x4 v = ((const f32x4*)partial)[(size_t)k * n4 + i];
    s[0] += v[0]; s[1] += v[1]; s[2] += v[2]; s[3] += v[3];
  }
  f32x4 bb = ((const f32x4*)b1)[i & (H1_DIM / 4 - 1)];
  u16x4 o;
#pragma unroll
  for (int j = 0; j < 4; ++j)
    o[j] = f2b(fmaxf(s[j] + bb[j], 0.f));
  ((u16x4*)h1b)[i] = o;
}

// ---------------- K2: layer-2 GEMM bf16, bias+relu fused -> h2 bf16 ----------------
__global__ __launch_bounds__(256, 2)
void k_gemm2(const u16* __restrict__ h1b, const u16* __restrict__ W2b,
             const float* __restrict__ b2, u16* __restrict__ h2b) {
  const int m0 = blockIdx.x * 128;
  const int n0 = blockIdx.y * 64;
  const int tid  = threadIdx.x;
  const int lane = tid & 63;
  const int wid  = tid >> 6;
  const int wr = wid >> 1, wc = wid & 1;
  const int c15 = lane & 15, j4 = lane >> 4;

  __shared__ u16 lsA[2][128 * 32];
  __shared__ u16 lsB[2][64 * 32];

  f32x4 zero = {0.f, 0.f, 0.f, 0.f};
  f32x4 acc[4][2];
#pragma unroll
  for (int m = 0; m < 4; ++m) { acc[m][0] = zero; acc[m][1] = zero; }

  auto stage = [&](int buf, int kt) {
    const int k0 = kt * 32;
#pragma unroll
    for (int c = 0; c < 2; ++c) {
      int lin = c * 256 + tid;
      int row = lin >> 2, slot = lin & 3;
      int gslot = slot ^ ((row >> 1) & 3);
      gld16(h1b + (size_t)(m0 + row) * H1_DIM + k0 + gslot * 8, &lsA[buf][lin * 8]);
    }
    {
      int lin = tid;
      int row = lin >> 2, slot = lin & 3;
      int gslot = slot ^ ((row >> 1) & 3);
      gld16(W2b + (size_t)(n0 + row) * H1_DIM + k0 + gslot * 8, &lsB[buf][lin * 8]);
    }
  };

  stage(0, 0);
  __syncthreads();
  int buf = 0;
  const int nkt = H1_DIM / 32;   // 16
  for (int t = 0; t < nkt; ++t) {
    if (t + 1 < nkt) stage(buf ^ 1, t + 1);
    Frag bfr[2];
#pragma unroll
    for (int n = 0; n < 2; ++n) {
      int row = wc * 32 + n * 16 + c15;
      int slot = j4 ^ ((row >> 1) & 3);
      bfr[n].s = *(const short8*)&lsB[buf][row * 32 + slot * 8];
    }
    Frag afr[4];
#pragma unroll
    for (int m = 0; m < 4; ++m) {
      int row = wr * 64 + m * 16 + c15;
      int slot = j4 ^ ((row >> 1) & 3);
      afr[m].s = *(const short8*)&lsA[buf][row * 32 + slot * 8];
    }
#pragma unroll
    for (int m = 0; m < 4; ++m)
#pragma unroll
      for (int n = 0; n < 2; ++n)
        acc[m][n] = __builtin_amdgcn_mfma_f32_16x16x32_bf16(afr[m].s, bfr[n].s, acc[m][n], 0, 0, 0);
    __syncthreads();
    buf ^= 1;
  }

  float b2v[2];
  b2v[0] = b2[n0 + wc * 32 + c15];
  b2v[1] = b2[n0 + wc * 32 + 16 + c15];
#pragma unroll
  for (int m = 0; m < 4; ++m)
#pragma unroll
    for (int n = 0; n < 2; ++n)
#pragma unroll
      for (int r = 0; r < 4; ++r) {
        int row = m0 + wr * 64 + m * 16 + j4 * 4 + r;
        int col = n0 + wc * 32 + n * 16 + c15;
        h2b[(size_t)row * H2_DIM + col] = f2b(fmaxf(acc[m][n][r] + b2v[n], 0.f));
      }
}

// ---------------- K3: fused heads (R11 restructure) ----------------
// Block = 128 B-rows x 16 heads; grid 64 x 8 = 512 = 2 blocks/CU.
// pg = blockIdx&7 XCD-pins the p-group's 512KB W3f slice into L2.
// h2 tile (64 KB, swizzled) staged ONCE via gld16 + one barrier; then the
// chunk loop is barrier-free read-only LDS. B-frags load reg-direct from
// fragment-linear W3f (1KB coalesced per frag). L4 dot fused in-register.
__global__ __launch_bounds__(512, 4)
void k_heads(const u16* __restrict__ h2b, const u16* __restrict__ W3f,
             const float* __restrict__ b3, const float* __restrict__ W4,
             const float* __restrict__ b4, float* __restrict__ out) {
  const int pg = blockIdx.x & 7;        // p-group (16 heads), XCD-pinned
  const int mb = blockIdx.x >> 3;       // m-block (128 rows)
  const int m0 = mb * 128;

  const int tid  = threadIdx.x;
  const int lane = tid & 63;
  const int w    = tid >> 6;
  const int mh = w & 1;                 // 64-row half
  const int hs = w >> 1;                // head slot 0..3
  const int c15 = lane & 15, j4 = lane >> 4;

  __shared__ u16 lsA[128 * 256];        // 64 KB; row=512B=32 slots; phys = g ^ (row&7)

  // stage h2 tile once: 8 x 512thr x 16B (linear dest, inverse-swizzled src)
#pragma unroll
  for (int c = 0; c < 8; ++c) {
    int lin = c * 512 + tid;
    int row = lin >> 5, slot = lin & 31;
    int gslot = slot ^ (row & 7);
    gld16(h2b + (size_t)(m0 + row) * H2_DIM + gslot * 8, (u16*)lsA + lin * 8);
  }
  __syncthreads();                      // one drain; rest is barrier-free

  f32x4 zero = {0.f, 0.f, 0.f, 0.f};

  for (int chunk = 0; chunk < 4; ++chunk) {
    const int p = pg * 16 + chunk * 4 + hs;

    f32x4 acc[4][4];
#pragma unroll
    for (int m = 0; m < 4; ++m)
#pragma unroll
      for (int n = 0; n < 4; ++n) acc[m][n] = zero;

#pragma unroll
    for (int kt = 0; kt < 8; ++kt) {
      Frag bfr[4];
#pragma unroll
      for (int nf = 0; nf < 4; ++nf)
        bfr[nf].s = *(const short8*)(W3f + (((size_t)(p * 4 + nf) * 8 + kt) * 64 + lane) * 8);
      Frag afr[4];
#pragma unroll
      for (int mf = 0; mf < 4; ++mf) {
        int row = mh * 64 + mf * 16 + c15;
        int g = kt * 4 + j4;
        int phys = g ^ (row & 7);
        afr[mf].s = *(const short8*)&lsA[row * 256 + phys * 8];
      }
#pragma unroll
      for (int mf = 0; mf < 4; ++mf)
#pragma unroll
        for (int nf = 0; nf < 4; ++nf)
          acc[mf][nf] = __builtin_amdgcn_mfma_f32_16x16x32_bf16(afr[mf].s, bfr[nf].s, acc[mf][nf], 0, 0, 0);
    }

    // fused L4: relu + dot W4 + bias; reduce over the 16 a-lanes
    float w4v[4], b3v[4];
#pragma unroll
    for (int nf = 0; nf < 4; ++nf) {
      w4v[nf] = W4[p * A_DIM + nf * 16 + c15];
      b3v[nf] = b3[p * A_DIM + nf * 16 + c15];
    }
    const float b4v = b4[p];

    float s[4][4];
#pragma unroll
    for (int mf = 0; mf < 4; ++mf)
#pragma unroll
      for (int r = 0; r < 4; ++r) s[mf][r] = 0.f;
#pragma unroll
    for (int mf = 0; mf < 4; ++mf)
#pragma unroll
      for (int nf = 0; nf < 4; ++nf)
#pragma unroll
        for (int r = 0; r < 4; ++r) {
          float v = fmaxf(acc[mf][nf][r] + b3v[nf], 0.f);
          s[mf][r] += v * w4v[nf];
        }
#pragma unroll
    for (int mf = 0; mf < 4; ++mf)
#pragma unroll
      for (int r = 0; r < 4; ++r) {
        float v = s[mf][r];
        v += __shfl_xor(v, 1);
        v += __shfl_xor(v, 2);
        v += __shfl_xor(v, 4);
        v += __shfl_xor(v, 8);
        s[mf][r] = v;
      }
    if (c15 == 0) {
#pragma unroll
      for (int mf = 0; mf < 4; ++mf)
#pragma unroll
        for (int r = 0; r < 4; ++r) {
          int row = m0 + mh * 64 + mf * 16 + j4 * 4 + r;
          out[(size_t)row * P_DIM + p] = s[mf][r] + b4v;
        }
    }
  }
}

extern "C" void kernel_launch(void* const* d_in, const int* in_sizes, int n_in,
                              void* d_out, int out_size, void* d_ws, size_t ws_size,
                              hipStream_t stream) {
  const float* x  = (const float*)d_in[0];
  const float* W1 = (const float*)d_in[1];
  const float* b1 = (const float*)d_in[2];
  const float* W2 = (const float*)d_in[3];
  const float* b2 = (const float*)d_in[4];
  const float* W3 = (const float*)d_in[5];
  const float* b3 = (const float*)d_in[6];
  const float* W4 = (const float*)d_in[7];
  const float* b4 = (const float*)d_in[8];
  float* out = (float*)d_out;

  char* ws = (char*)d_ws;
  u16*   W1f  = (u16*)(ws);                    // 20,480,000 B (fragment-linear)
  u16*   W2b  = (u16*)(ws + 20480000);         //    262,144 B
  u16*   W3f  = (u16*)(ws + 20742144);         //  4,194,304 B (fragment-linear)
  u16*   h1b  = (u16*)(ws + 24936448);         //  8,388,608 B
  u16*   h2b  = (u16*)(ws + 33325056);         //  4,194,304 B
  float* part = (float*)(ws + 37519360);       // 8 x 16 MB = 134,217,728 B (end ~172 MB)

  k_convert_w1frag<<<dim3((1280000 + 255) / 256), dim3(256), 0, stream>>>(W1, W1f);
  k_convert<<<dim3(131072 / 4 / 256), dim3(256), 0, stream>>>(W2, W2b, 131072 / 4);
  k_convert_w3frag<<<dim3(262144 / 256), dim3(256), 0, stream>>>(W3, W3f);

  k_gemm1<<<dim3(128 * SPLITK), dim3(512), 0, stream>>>(x, W1f, part);
  k_reduce1<<<dim3(B_DIM * H1_DIM / 4 / 256), dim3(256), 0, stream>>>(part, b1, h1b);
  k_gemm2<<<dim3(64, 4), dim3(256), 0, stream>>>(h1b, W2b, b2, h2b);
  k_heads<<<dim3(512), dim3(512), 0, stream>>>(h2b, W3f, b3, W4, b4, out);
}

// Round 12
// 451.120 us; speedup vs baseline: 1.0094x; 1.0094x over previous
//
#include <hip/hip_runtime.h>
#include <hip/hip_bf16.h>
#include <stdint.h>

typedef unsigned short u16;
typedef __attribute__((ext_vector_type(8))) short short8;
typedef __attribute__((ext_vector_type(8))) u16   u16x8;
typedef __attribute__((ext_vector_type(4))) u16   u16x4;
typedef __attribute__((ext_vector_type(4))) float f32x4;

#define B_DIM  8192
#define G_DIM  20000
#define H1_DIM 512
#define H2_DIM 256
#define P_DIM  128
#define A_DIM  64
#define SPLITK 8
#define NKT_ALL 625   // 20000 / 32

union Frag { short8 s; u16x8 u; };

__device__ __forceinline__ u16 f2b(float f) {
  union { __hip_bfloat16 b; u16 u; } c;
  c.b = __float2bfloat16(f);
  return c.u;
}

__device__ __forceinline__ void gld16(const void* g, void* l) {
  __builtin_amdgcn_global_load_lds(
      (const __attribute__((address_space(1))) void*)g,
      (__attribute__((address_space(3))) void*)l, 16, 0, 0);
}

// ---------------- prep: f32 -> bf16 convert (vectorized) ----------------
__global__ void k_convert(const float* __restrict__ src, u16* __restrict__ dst, int n4) {
  int i = blockIdx.x * 256 + threadIdx.x;
  if (i >= n4) return;
  f32x4 v = ((const f32x4*)src)[i];
  u16x4 o;
  o[0] = f2b(v[0]); o[1] = f2b(v[1]);
  o[2] = f2b(v[2]); o[3] = f2b(v[3]);
  ((u16x4*)dst)[i] = o;
}

// ---------------- prep: W1 f32 -> MFMA-fragment-linear bf16 ----------------
// chunk ot = (rowblk*625 + kt)*64 + lane  ->  W1[rowblk*16 + (lane&15)]
//                                             [kt*32 + (lane>>4)*8 + 0..7]
__global__ void k_convert_w1frag(const float* __restrict__ W1, u16* __restrict__ W1f) {
  int ot = blockIdx.x * 256 + threadIdx.x;       // 0 .. 1,279,999
  if (ot >= (H1_DIM / 16) * NKT_ALL * 64) return;
  int rowblk = ot / (NKT_ALL * 64);
  int rem    = ot - rowblk * (NKT_ALL * 64);
  int kt     = rem >> 6;
  int lane   = rem & 63;
  int row = rowblk * 16 + (lane & 15);
  int col = kt * 32 + (lane >> 4) * 8;
  const float* src = W1 + (size_t)row * G_DIM + col;
  f32x4 v0 = *(const f32x4*)src;
  f32x4 v1 = *(const f32x4*)(src + 4);
  u16x8 o;
#pragma unroll
  for (int i = 0; i < 4; ++i) { o[i] = f2b(v0[i]); o[i + 4] = f2b(v1[i]); }
  ((u16x8*)W1f)[ot] = o;
}

// ---------------- prep: W3[p][h][a] f32 -> W3T[p][a][h] bf16 ----------------
__global__ void k_transpose_w3(const float* __restrict__ W3, u16* __restrict__ W3T) {
  int idx = blockIdx.x * 256 + threadIdx.x;     // = (p*64+a)*256 + h
  if (idx >= P_DIM * H2_DIM * A_DIM) return;
  int h = idx & (H2_DIM - 1);
  int a = (idx >> 8) & (A_DIM - 1);
  int p = idx >> 14;
  W3T[idx] = f2b(W3[((size_t)p * H2_DIM + h) * A_DIM + a]);
}

// ---------------- K1: layer-1 GEMM (R12: lean blocks, 3/CU) ----------------
// BM=32, BN=512 (X read once), BK=64 supers, 256 thr / 4 waves, wave=32x128,
// acc[2][8]=64 VGPR. B reg-direct from fragment-linear W1f (ks=blockIdx&7
// XCD-pins the 2.56MB slice into L2 — R7-verified), loaded inline per kt:
// 3 independent blocks/CU provide the latency overlap (R1/m114 evidence).
// A staged 1 tile ahead via regs -> 4KB LDS dbuf. Plain __syncthreads.
__global__ __launch_bounds__(256, 3)   // 3 blocks/CU, VGPR cap 170, LDS 8KB
void k_gemm1(const float* __restrict__ X, const u16* __restrict__ W1f,
             float* __restrict__ partial) {
  const int ks = blockIdx.x & 7;
  const int m0 = (blockIdx.x >> 3) * 32;               // 256 m-blocks
  const int kt_begin = (ks == 0) ? 0 : (ks * 78 + 1);  // {79, 78x7} of 625
  const int nkt = (ks == 0) ? 79 : 78;

  const int tid  = threadIdx.x;
  const int lane = tid & 63;
  const int w    = tid >> 6;            // wave 0..3 -> N cols w*128..
  const int c15 = lane & 15, j4 = lane >> 4;
  const int w8 = w * 8;

  __shared__ u16 lsA[2][32 * 64];       // 4 KB/buf: 32 rows x 128B (8 slots of 16B)
                                        // phys slot = g ^ (row&7)

  // A staging: thread -> row tid>>3 (0..31), granule g=tid&7 (8 f32 -> 8 bf16)
  const int aRow = tid >> 3;
  const int aG   = tid & 7;
  const int aPhysU16 = aRow * 64 + ((aG ^ (aRow & 7)) * 8);
  const float* aSrc0 = X + (size_t)(m0 + aRow) * G_DIM + aG * 8;

  f32x4 zero = {0.f, 0.f, 0.f, 0.f};
  f32x4 acc[2][8];
#pragma unroll
  for (int m = 0; m < 2; ++m)
#pragma unroll
    for (int n = 0; n < 8; ++n) acc[m][n] = zero;

  f32x4 ar0, ar1;
  auto loadA = [&](int kt) {            // 64-col (2-kt) tile starting at kt
    const float* src = aSrc0 + (size_t)kt * 32;
    ar0 = *(const f32x4*)src;
    ar1 = *(const f32x4*)(src + 4);
  };
  auto writeA = [&](int buf) {
    u16x8 o;
#pragma unroll
    for (int i = 0; i < 4; ++i) { o[i] = f2b(ar0[i]); o[i + 4] = f2b(ar1[i]); }
    *(u16x8*)&lsA[buf][aPhysU16] = o;
  };

  // ---- prologue: A tile 0 (kt 0,1) -> LDS buf0 ----
  loadA(kt_begin);
  writeA(0);
  __syncthreads();

  const int nsuper = 39;                // kt 0..77
  for (int T = 0; T < nsuper; ++T) {
    const int buf = T & 1;
    const int kt0 = kt_begin + 2 * T;
    const int ktN = 2 * (T + 1);
    const int ktNext = kt_begin + ((ktN < nkt) ? ktN : (nkt - 1));

    loadA(ktNext);                      // A tile T+1 (cover: whole body)

#pragma unroll
    for (int half = 0; half < 2; ++half) {
      const int kt = kt0 + half;
      Frag bfr[8];
#pragma unroll
      for (int n = 0; n < 8; ++n)
        bfr[n].s = *(const short8*)(W1f + ((size_t)((w8 + n) * NKT_ALL + kt) * 64 + lane) * 8);
      Frag afr[2];
#pragma unroll
      for (int m = 0; m < 2; ++m) {
        int row = m * 16 + c15;
        int g = half * 4 + j4;
        int phys = g ^ (row & 7);
        afr[m].s = *(const short8*)&lsA[buf][row * 64 + phys * 8];
      }
#pragma unroll
      for (int m = 0; m < 2; ++m)
#pragma unroll
        for (int n = 0; n < 8; ++n)
          acc[m][n] = __builtin_amdgcn_mfma_f32_16x16x32_bf16(afr[m].s, bfr[n].s, acc[m][n], 0, 0, 0);
    }

    writeA(buf ^ 1);                    // A tile T+1
    __syncthreads();
  }

  if (nkt == 79) {                      // ks==0 epilogue: kt 78 (in buf1, half 0)
    const int kt = kt_begin + 78;
    Frag bfr[8];
#pragma unroll
    for (int n = 0; n < 8; ++n)
      bfr[n].s = *(const short8*)(W1f + ((size_t)((w8 + n) * NKT_ALL + kt) * 64 + lane) * 8);
    Frag afr[2];
#pragma unroll
    for (int m = 0; m < 2; ++m) {
      int row = m * 16 + c15;
      int phys = j4 ^ (row & 7);
      afr[m].s = *(const short8*)&lsA[1][row * 64 + phys * 8];
    }
#pragma unroll
    for (int m = 0; m < 2; ++m)
#pragma unroll
      for (int n = 0; n < 8; ++n)
        acc[m][n] = __builtin_amdgcn_mfma_f32_16x16x32_bf16(afr[m].s, bfr[n].s, acc[m][n], 0, 0, 0);
  }

  float* outp = partial + ((size_t)ks * B_DIM + m0) * H1_DIM;
#pragma unroll
  for (int m = 0; m < 2; ++m)
#pragma unroll
    for (int n = 0; n < 8; ++n)
#pragma unroll
      for (int r = 0; r < 4; ++r) {
        int row = m * 16 + j4 * 4 + r;
        int col = w * 128 + n * 16 + c15;
        outp[(size_t)row * H1_DIM + col] = acc[m][n][r];
      }
}

// ---------------- K1b: sum 8 partials + bias + relu -> h1 bf16 ----------------
__global__ void k_reduce1(const float* __restrict__ partial, const float* __restrict__ b1,
                          u16* __restrict__ h1b) {
  const int n4 = B_DIM * H1_DIM / 4;
  int i = blockIdx.x * 256 + threadIdx.x;
  if (i >= n4) return;
  f32x4 s = ((const f32x4*)partial)[i];
#pragma unroll
  for (int k = 1; k < SPLITK; ++k) {
    f32x4 v = ((const f32x4*)partial)[(size_t)k * n4 + i];
    s[0] += v[0]; s[1] += v[1]; s[2] += v[2]; s[3] += v[3];
  }
  f32x4 bb = ((const f32x4*)b1)[i & (H1_DIM / 4 - 1)];
  u16x4 o;
#pragma unroll
  for (int j = 0; j < 4; ++j)
    o[j] = f2b(fmaxf(s[j] + bb[j], 0.f));
  ((u16x4*)h1b)[i] = o;
}

// ---------------- K2: layer-2 GEMM bf16, bias+relu fused -> h2 bf16 ----------------
__global__ __launch_bounds__(256, 2)
void k_gemm2(const u16* __restrict__ h1b, const u16* __restrict__ W2b,
             const float* __restrict__ b2, u16* __restrict__ h2b) {
  const int m0 = blockIdx.x * 128;
  const int n0 = blockIdx.y * 64;
  const int tid  = threadIdx.x;
  const int lane = tid & 63;
  const int wid  = tid >> 6;
  const int wr = wid >> 1, wc = wid & 1;
  const int c15 = lane & 15, j4 = lane >> 4;

  __shared__ u16 lsA[2][128 * 32];
  __shared__ u16 lsB[2][64 * 32];

  f32x4 zero = {0.f, 0.f, 0.f, 0.f};
  f32x4 acc[4][2];
#pragma unroll
  for (int m = 0; m < 4; ++m) { acc[m][0] = zero; acc[m][1] = zero; }

  auto stage = [&](int buf, int kt) {
    const int k0 = kt * 32;
#pragma unroll
    for (int c = 0; c < 2; ++c) {
      int lin = c * 256 + tid;
      int row = lin >> 2, slot = lin & 3;
      int gslot = slot ^ ((row >> 1) & 3);
      gld16(h1b + (size_t)(m0 + row) * H1_DIM + k0 + gslot * 8, &lsA[buf][lin * 8]);
    }
    {
      int lin = tid;
      int row = lin >> 2, slot = lin & 3;
      int gslot = slot ^ ((row >> 1) & 3);
      gld16(W2b + (size_t)(n0 + row) * H1_DIM + k0 + gslot * 8, &lsB[buf][lin * 8]);
    }
  };

  stage(0, 0);
  __syncthreads();
  int buf = 0;
  const int nkt = H1_DIM / 32;   // 16
  for (int t = 0; t < nkt; ++t) {
    if (t + 1 < nkt) stage(buf ^ 1, t + 1);
    Frag bfr[2];
#pragma unroll
    for (int n = 0; n < 2; ++n) {
      int row = wc * 32 + n * 16 + c15;
      int slot = j4 ^ ((row >> 1) & 3);
      bfr[n].s = *(const short8*)&lsB[buf][row * 32 + slot * 8];
    }
    Frag afr[4];
#pragma unroll
    for (int m = 0; m < 4; ++m) {
      int row = wr * 64 + m * 16 + c15;
      int slot = j4 ^ ((row >> 1) & 3);
      afr[m].s = *(const short8*)&lsA[buf][row * 32 + slot * 8];
    }
#pragma unroll
    for (int m = 0; m < 4; ++m)
#pragma unroll
      for (int n = 0; n < 2; ++n)
        acc[m][n] = __builtin_amdgcn_mfma_f32_16x16x32_bf16(afr[m].s, bfr[n].s, acc[m][n], 0, 0, 0);
    __syncthreads();
    buf ^= 1;
  }

  float b2v[2];
  b2v[0] = b2[n0 + wc * 32 + c15];
  b2v[1] = b2[n0 + wc * 32 + 16 + c15];
#pragma unroll
  for (int m = 0; m < 4; ++m)
#pragma unroll
    for (int n = 0; n < 2; ++n)
#pragma unroll
      for (int r = 0; r < 4; ++r) {
        int row = m0 + wr * 64 + m * 16 + j4 * 4 + r;
        int col = n0 + wc * 32 + n * 16 + c15;
        h2b[(size_t)row * H2_DIM + col] = f2b(fmaxf(acc[m][n][r] + b2v[n], 0.f));
      }
}

// ---------------- K3: fused heads (reverted to R10 version) ----------------
__global__ __launch_bounds__(256, 2)
void k_heads(const u16* __restrict__ h2b, const u16* __restrict__ W3T,
             const float* __restrict__ b3, const float* __restrict__ W4,
             const float* __restrict__ b4, float* __restrict__ out) {
  const int m0 = blockIdx.x * 128;
  const int p0 = blockIdx.y * 2;
  const int tid  = threadIdx.x;
  const int lane = tid & 63;
  const int wid  = tid >> 6;
  const int wr = wid >> 1, wc = wid & 1;
  const int c15 = lane & 15, j4 = lane >> 4;

  __shared__ u16 lsA[2][128 * 64];
  __shared__ u16 lsB[2][128 * 64];

  f32x4 zero = {0.f, 0.f, 0.f, 0.f};
  f32x4 acc[4][4];
#pragma unroll
  for (int m = 0; m < 4; ++m)
#pragma unroll
    for (int n = 0; n < 4; ++n) acc[m][n] = zero;

  auto stage = [&](int buf, int kt) {
    const int k0 = kt * 64;
#pragma unroll
    for (int c = 0; c < 4; ++c) {
      int lin = c * 256 + tid;
      int row = lin >> 3, slot = lin & 7;
      int gslot = slot ^ (row & 7);
      gld16(h2b + (size_t)(m0 + row) * H2_DIM + k0 + gslot * 8, &lsA[buf][lin * 8]);
    }
#pragma unroll
    for (int c = 0; c < 4; ++c) {
      int lin = c * 256 + tid;
      int row = lin >> 3, slot = lin & 7;
      int gslot = slot ^ (row & 7);
      gld16(W3T + ((size_t)(p0 * 64 + row)) * H2_DIM + k0 + gslot * 8, &lsB[buf][lin * 8]);
    }
  };

  stage(0, 0);
  __syncthreads();
  int buf = 0;
  const int nkt = H2_DIM / 64;   // 4
  for (int t = 0; t < nkt; ++t) {
    if (t + 1 < nkt) stage(buf ^ 1, t + 1);
#pragma unroll
    for (int kk = 0; kk < 2; ++kk) {
      Frag bfr[4];
#pragma unroll
      for (int n = 0; n < 4; ++n) {
        int row = wc * 64 + n * 16 + c15;
        int slot = (kk * 4 + j4) ^ (row & 7);
        bfr[n].s = *(const short8*)&lsB[buf][row * 64 + slot * 8];
      }
      Frag afr[4];
#pragma unroll
      for (int m = 0; m < 4; ++m) {
        int row = wr * 64 + m * 16 + c15;
        int slot = (kk * 4 + j4) ^ (row & 7);
        afr[m].s = *(const short8*)&lsA[buf][row * 64 + slot * 8];
      }
#pragma unroll
      for (int m = 0; m < 4; ++m)
#pragma unroll
        for (int n = 0; n < 4; ++n)
          acc[m][n] = __builtin_amdgcn_mfma_f32_16x16x32_bf16(afr[m].s, bfr[n].s, acc[m][n], 0, 0, 0);
    }
    __syncthreads();
    buf ^= 1;
  }

  const int p = p0 + wc;
  float w4v[4], b3v[4];
#pragma unroll
  for (int n = 0; n < 4; ++n) {
    w4v[n] = W4[p * A_DIM + n * 16 + c15];
    b3v[n] = b3[p * A_DIM + n * 16 + c15];
  }
  const float b4v = b4[p];

  float s[4][4];
#pragma unroll
  for (int m = 0; m < 4; ++m)
#pragma unroll
    for (int r = 0; r < 4; ++r) s[m][r] = 0.f;
#pragma unroll
  for (int m = 0; m < 4; ++m)
#pragma unroll
    for (int n = 0; n < 4; ++n)
#pragma unroll
      for (int r = 0; r < 4; ++r) {
        float v = fmaxf(acc[m][n][r] + b3v[n], 0.f);
        s[m][r] += v * w4v[n];
      }
#pragma unroll
  for (int m = 0; m < 4; ++m)
#pragma unroll
    for (int r = 0; r < 4; ++r) {
      float v = s[m][r];
      v += __shfl_xor(v, 1);
      v += __shfl_xor(v, 2);
      v += __shfl_xor(v, 4);
      v += __shfl_xor(v, 8);
      s[m][r] = v;
    }
  if (c15 == 0) {
#pragma unroll
    for (int m = 0; m < 4; ++m)
#pragma unroll
      for (int r = 0; r < 4; ++r) {
        int row = m0 + wr * 64 + m * 16 + j4 * 4 + r;
        out[(size_t)row * P_DIM + p] = s[m][r] + b4v;
      }
  }
}

extern "C" void kernel_launch(void* const* d_in, const int* in_sizes, int n_in,
                              void* d_out, int out_size, void* d_ws, size_t ws_size,
                              hipStream_t stream) {
  const float* x  = (const float*)d_in[0];
  const float* W1 = (const float*)d_in[1];
  const float* b1 = (const float*)d_in[2];
  const float* W2 = (const float*)d_in[3];
  const float* b2 = (const float*)d_in[4];
  const float* W3 = (const float*)d_in[5];
  const float* b3 = (const float*)d_in[6];
  const float* W4 = (const float*)d_in[7];
  const float* b4 = (const float*)d_in[8];
  float* out = (float*)d_out;

  char* ws = (char*)d_ws;
  u16*   W1f  = (u16*)(ws);                    // 20,480,000 B (fragment-linear)
  u16*   W2b  = (u16*)(ws + 20480000);         //    262,144 B
  u16*   W3T  = (u16*)(ws + 20742144);         //  4,194,304 B
  u16*   h1b  = (u16*)(ws + 24936448);         //  8,388,608 B
  u16*   h2b  = (u16*)(ws + 33325056);         //  4,194,304 B
  float* part = (float*)(ws + 37519360);       // 8 x 16 MB = 134,217,728 B (end ~172 MB)

  k_convert_w1frag<<<dim3((1280000 + 255) / 256), dim3(256), 0, stream>>>(W1, W1f);
  k_convert<<<dim3(131072 / 4 / 256), dim3(256), 0, stream>>>(W2, W2b, 131072 / 4);
  k_transpose_w3<<<dim3(2097152 / 256), dim3(256), 0, stream>>>(W3, W3T);

  k_gemm1<<<dim3(256 * SPLITK), dim3(256), 0, stream>>>(x, W1f, part);
  k_reduce1<<<dim3(B_DIM * H1_DIM / 4 / 256), dim3(256), 0, stream>>>(part, b1, h1b);
  k_gemm2<<<dim3(64, 4), dim3(256), 0, stream>>>(h1b, W2b, b2, h2b);
  k_heads<<<dim3(64, 64), dim3(256), 0, stream>>>(h2b, W3T, b3, W4, b4, out);
}

// Round 13
// 349.632 us; speedup vs baseline: 1.3023x; 1.2903x over previous
//
#include <hip/hip_runtime.h>
#include <hip/hip_bf16.h>
#include <stdint.h>

typedef unsigned short u16;
typedef __attribute__((ext_vector_type(8))) short short8;
typedef __attribute__((ext_vector_type(8))) u16   u16x8;
typedef __attribute__((ext_vector_type(4))) u16   u16x4;
typedef __attribute__((ext_vector_type(4))) float f32x4;

#define B_DIM  8192
#define G_DIM  20000
#define H1_DIM 512
#define H2_DIM 256
#define P_DIM  128
#define A_DIM  64
#define SPLITK 8
#define NKT_ALL 625   // 20000 / 32

union Frag { short8 s; u16x8 u; };

__device__ __forceinline__ u16 f2b(float f) {
  union { __hip_bfloat16 b; u16 u; } c;
  c.b = __float2bfloat16(f);
  return c.u;
}

__device__ __forceinline__ void gld16(const void* g, void* l) {
  __builtin_amdgcn_global_load_lds(
      (const __attribute__((address_space(1))) void*)g,
      (__attribute__((address_space(3))) void*)l, 16, 0, 0);
}

// ---------------- prep: f32 -> bf16 convert (vectorized) ----------------
__global__ void k_convert(const float* __restrict__ src, u16* __restrict__ dst, int n4) {
  int i = blockIdx.x * 256 + threadIdx.x;
  if (i >= n4) return;
  f32x4 v = ((const f32x4*)src)[i];
  u16x4 o;
  o[0] = f2b(v[0]); o[1] = f2b(v[1]);
  o[2] = f2b(v[2]); o[3] = f2b(v[3]);
  ((u16x4*)dst)[i] = o;
}

// ---------------- prep: W1 f32 -> MFMA-fragment-linear bf16 ----------------
// chunk ot = (rowblk*625 + kt)*64 + lane  ->  W1[rowblk*16 + (lane&15)]
//                                             [kt*32 + (lane>>4)*8 + 0..7]
__global__ void k_convert_w1frag(const float* __restrict__ W1, u16* __restrict__ W1f) {
  int ot = blockIdx.x * 256 + threadIdx.x;       // 0 .. 1,279,999
  if (ot >= (H1_DIM / 16) * NKT_ALL * 64) return;
  int rowblk = ot / (NKT_ALL * 64);
  int rem    = ot - rowblk * (NKT_ALL * 64);
  int kt     = rem >> 6;
  int lane   = rem & 63;
  int row = rowblk * 16 + (lane & 15);
  int col = kt * 32 + (lane >> 4) * 8;
  const float* src = W1 + (size_t)row * G_DIM + col;
  f32x4 v0 = *(const f32x4*)src;
  f32x4 v1 = *(const f32x4*)(src + 4);
  u16x8 o;
#pragma unroll
  for (int i = 0; i < 4; ++i) { o[i] = f2b(v0[i]); o[i + 4] = f2b(v1[i]); }
  ((u16x8*)W1f)[ot] = o;
}

// ---------------- prep: W3 f32 -> MFMA-fragment-linear bf16 ----------------
// chunk ot = ((p*4 + nf)*8 + kt)*64 + lane
//   element j = W3[p][h = kt*32 + (lane>>4)*8 + j][a = nf*16 + (lane&15)]
// (refcheck-verified in R11)
__global__ void k_convert_w3frag(const float* __restrict__ W3, u16* __restrict__ W3f) {
  int ot = blockIdx.x * 256 + threadIdx.x;       // 0 .. 262,143
  if (ot >= P_DIM * 4 * 8 * 64) return;
  int p    = ot >> 11;
  int rem  = ot & 2047;
  int nf   = rem >> 9;
  int kt   = (rem >> 6) & 7;
  int lane = ot & 63;
  int a  = nf * 16 + (lane & 15);
  int h0 = kt * 32 + (lane >> 4) * 8;
  u16x8 o;
#pragma unroll
  for (int j = 0; j < 8; ++j)
    o[j] = f2b(W3[((size_t)p * H2_DIM + h0 + j) * A_DIM + a]);
  ((u16x8*)W3f)[ot] = o;
}

// ---------------- K1: layer-1 GEMM (R10-exact: best measured) ----------------
__global__ __launch_bounds__(512, 4)
void k_gemm1(const float* __restrict__ X, const u16* __restrict__ W1f,
             float* __restrict__ partial) {
  const int ks = blockIdx.x & 7;
  const int m0 = (blockIdx.x >> 3) * 64;
  const int kt_begin = (ks == 0) ? 0 : (ks * 78 + 1);   // {79, 78x7} of 625
  const int nkt = (ks == 0) ? 79 : 78;

  const int tid  = threadIdx.x;
  const int lane = tid & 63;
  const int w    = tid >> 6;
  const int c15 = lane & 15, j4 = lane >> 4;
  const int w4 = w * 4;

  __shared__ u16 lsA[2][64 * 64];   // 8 KB/buf; phys slot = g ^ (row&7)

  const int aRow = tid >> 3;
  const int aG   = tid & 7;
  const int aPhysU16 = aRow * 64 + ((aG ^ (aRow & 7)) * 8);
  const float* aSrc0 = X + (size_t)(m0 + aRow) * G_DIM + aG * 8;

  f32x4 zero = {0.f, 0.f, 0.f, 0.f};
  f32x4 acc[4][4];
#pragma unroll
  for (int m = 0; m < 4; ++m)
#pragma unroll
    for (int n = 0; n < 4; ++n) acc[m][n] = zero;

  auto loadB = [&](int kt, Frag* br) {
#pragma unroll
    for (int n = 0; n < 4; ++n)
      br[n].s = *(const short8*)(W1f + ((size_t)((w4 + n) * NKT_ALL + kt) * 64 + lane) * 8);
  };
  f32x4 ar0, ar1;
  auto loadA = [&](int kt) {
    const float* src = aSrc0 + (size_t)kt * 32;
    ar0 = *(const f32x4*)src;
    ar1 = *(const f32x4*)(src + 4);
  };
  auto writeA = [&](int buf) {
    u16x8 o;
#pragma unroll
    for (int i = 0; i < 4; ++i) { o[i] = f2b(ar0[i]); o[i + 4] = f2b(ar1[i]); }
    *(u16x8*)&lsA[buf][aPhysU16] = o;
  };
  auto readAfr = [&](int buf, int half, Frag* afr) {
#pragma unroll
    for (int m = 0; m < 4; ++m) {
      int row = m * 16 + c15;
      int g = half * 4 + j4;
      int phys = g ^ (row & 7);
      afr[m].s = *(const short8*)&lsA[buf][row * 64 + phys * 8];
    }
  };

  Frag bfrE[4], bfrO[4];

  loadA(kt_begin);
  loadB(kt_begin, bfrE);
  writeA(0);
  asm volatile("s_waitcnt lgkmcnt(0)" ::: "memory");
  __builtin_amdgcn_s_barrier();
  __builtin_amdgcn_sched_barrier(0);

  const int nsuper = 39;
  for (int T = 0; T < nsuper; ++T) {
    const int buf = T & 1;
    const int kt0 = kt_begin + 2 * T;
    const int ktN = 2 * (T + 1);
    const int ktNext = kt_begin + ((ktN < nkt) ? ktN : (nkt - 1));

    loadA(ktNext);
    loadB(kt0 + 1, bfrO);

    Frag afr[4];
    readAfr(buf, 0, afr);
#pragma unroll
    for (int m = 0; m < 4; ++m)
#pragma unroll
      for (int n = 0; n < 4; ++n)
        acc[m][n] = __builtin_amdgcn_mfma_f32_16x16x32_bf16(afr[m].s, bfrE[n].s, acc[m][n], 0, 0, 0);

    loadB(ktNext, bfrE);

    readAfr(buf, 1, afr);
#pragma unroll
    for (int m = 0; m < 4; ++m)
#pragma unroll
      for (int n = 0; n < 4; ++n)
        acc[m][n] = __builtin_amdgcn_mfma_f32_16x16x32_bf16(afr[m].s, bfrO[n].s, acc[m][n], 0, 0, 0);

    writeA(buf ^ 1);
    asm volatile("s_waitcnt lgkmcnt(0)" ::: "memory");
    __builtin_amdgcn_s_barrier();
    __builtin_amdgcn_sched_barrier(0);
  }

  if (nkt == 79) {
    Frag afr[4];
    readAfr(1, 0, afr);
#pragma unroll
    for (int m = 0; m < 4; ++m)
#pragma unroll
      for (int n = 0; n < 4; ++n)
        acc[m][n] = __builtin_amdgcn_mfma_f32_16x16x32_bf16(afr[m].s, bfrE[n].s, acc[m][n], 0, 0, 0);
  }

  float* outp = partial + ((size_t)ks * B_DIM + m0) * H1_DIM;
#pragma unroll
  for (int m = 0; m < 4; ++m)
#pragma unroll
    for (int n = 0; n < 4; ++n)
#pragma unroll
      for (int r = 0; r < 4; ++r) {
        int row = m * 16 + j4 * 4 + r;
        int col = w * 64 + n * 16 + c15;
        outp[(size_t)row * H1_DIM + col] = acc[m][n][r];
      }
}

// ---------------- K1b: sum 8 partials + bias + relu -> h1 bf16 ----------------
__global__ void k_reduce1(const float* __restrict__ partial, const float* __restrict__ b1,
                          u16* __restrict__ h1b) {
  const int n4 = B_DIM * H1_DIM / 4;
  int i = blockIdx.x * 256 + threadIdx.x;
  if (i >= n4) return;
  f32x4 s = ((const f32x4*)partial)[i];
#pragma unroll
  for (int k = 1; k < SPLITK; ++k) {
    f32x4 v = ((const f32x4*)partial)[(size_t)k * n4 + i];
    s[0] += v[0]; s[1] += v[1]; s[2] += v[2]; s[3] += v[3];
  }
  f32x4 bb = ((const f32x4*)b1)[i & (H1_DIM / 4 - 1)];
  u16x4 o;
#pragma unroll
  for (int j = 0; j < 4; ++j)
    o[j] = f2b(fmaxf(s[j] + bb[j], 0.f));
  ((u16x4*)h1b)[i] = o;
}

// ---------------- K2: layer-2 GEMM bf16, bias+relu fused -> h2 bf16 ----------------
__global__ __launch_bounds__(256, 2)
void k_gemm2(const u16* __restrict__ h1b, const u16* __restrict__ W2b,
             const float* __restrict__ b2, u16* __restrict__ h2b) {
  const int m0 = blockIdx.x * 128;
  const int n0 = blockIdx.y * 64;
  const int tid  = threadIdx.x;
  const int lane = tid & 63;
  const int wid  = tid >> 6;
  const int wr = wid >> 1, wc = wid & 1;
  const int c15 = lane & 15, j4 = lane >> 4;

  __shared__ u16 lsA[2][128 * 32];
  __shared__ u16 lsB[2][64 * 32];

  f32x4 zero = {0.f, 0.f, 0.f, 0.f};
  f32x4 acc[4][2];
#pragma unroll
  for (int m = 0; m < 4; ++m) { acc[m][0] = zero; acc[m][1] = zero; }

  auto stage = [&](int buf, int kt) {
    const int k0 = kt * 32;
#pragma unroll
    for (int c = 0; c < 2; ++c) {
      int lin = c * 256 + tid;
      int row = lin >> 2, slot = lin & 3;
      int gslot = slot ^ ((row >> 1) & 3);
      gld16(h1b + (size_t)(m0 + row) * H1_DIM + k0 + gslot * 8, &lsA[buf][lin * 8]);
    }
    {
      int lin = tid;
      int row = lin >> 2, slot = lin & 3;
      int gslot = slot ^ ((row >> 1) & 3);
      gld16(W2b + (size_t)(n0 + row) * H1_DIM + k0 + gslot * 8, &lsB[buf][lin * 8]);
    }
  };

  stage(0, 0);
  __syncthreads();
  int buf = 0;
  const int nkt = H1_DIM / 32;   // 16
  for (int t = 0; t < nkt; ++t) {
    if (t + 1 < nkt) stage(buf ^ 1, t + 1);
    Frag bfr[2];
#pragma unroll
    for (int n = 0; n < 2; ++n) {
      int row = wc * 32 + n * 16 + c15;
      int slot = j4 ^ ((row >> 1) & 3);
      bfr[n].s = *(const short8*)&lsB[buf][row * 32 + slot * 8];
    }
    Frag afr[4];
#pragma unroll
    for (int m = 0; m < 4; ++m) {
      int row = wr * 64 + m * 16 + c15;
      int slot = j4 ^ ((row >> 1) & 3);
      afr[m].s = *(const short8*)&lsA[buf][row * 32 + slot * 8];
    }
#pragma unroll
    for (int m = 0; m < 4; ++m)
#pragma unroll
      for (int n = 0; n < 2; ++n)
        acc[m][n] = __builtin_amdgcn_mfma_f32_16x16x32_bf16(afr[m].s, bfr[n].s, acc[m][n], 0, 0, 0);
    __syncthreads();
    buf ^= 1;
  }

  float b2v[2];
  b2v[0] = b2[n0 + wc * 32 + c15];
  b2v[1] = b2[n0 + wc * 32 + 16 + c15];
#pragma unroll
  for (int m = 0; m < 4; ++m)
#pragma unroll
    for (int n = 0; n < 2; ++n)
#pragma unroll
      for (int r = 0; r < 4; ++r) {
        int row = m0 + wr * 64 + m * 16 + j4 * 4 + r;
        int col = n0 + wc * 32 + n * 16 + c15;
        h2b[(size_t)row * H2_DIM + col] = f2b(fmaxf(acc[m][n][r] + b2v[n], 0.f));
      }
}

// ---------------- K3: fused heads (R13: 8 heads/block, stage-once, no spill) ----------------
// 256 thr = 4 waves (2 m-halves x 2 head-slots); 8 heads per block via 4 chunks.
// Grid 16 x 64 = 1024 blocks; pg = blockIdx&15 -> each XCD sees 2 p-groups
// (512 KB W3f, L2-pinned). h2 tile 128x256 (64 KB, swizzled) staged ONCE,
// one barrier; chunk loop barrier-free. B reg-direct from fragment-linear W3f.
// __launch_bounds__(256,2): VGPR cap 256 -> no spill (R11's failure mode).
__global__ __launch_bounds__(256, 2)
void k_heads(const u16* __restrict__ h2b, const u16* __restrict__ W3f,
             const float* __restrict__ b3, const float* __restrict__ W4,
             const float* __restrict__ b4, float* __restrict__ out) {
  const int pg = blockIdx.x & 15;       // p-group (8 heads)
  const int mb = blockIdx.x >> 4;       // m-block (128 rows)
  const int m0 = mb * 128;

  const int tid  = threadIdx.x;
  const int lane = tid & 63;
  const int w    = tid >> 6;
  const int mh = w & 1;                 // 64-row half
  const int hs = w >> 1;                // head slot 0/1
  const int c15 = lane & 15, j4 = lane >> 4;

  __shared__ u16 lsA[128 * 256];        // 64 KB; row=512B=32 slots; phys = slot ^ (row&7)

  // stage h2 tile once: 16 x 256thr x 16B (linear dest, inverse-swizzled src)
#pragma unroll
  for (int c = 0; c < 16; ++c) {
    int lin = c * 256 + tid;
    int row = lin >> 5, slot = lin & 31;
    int gslot = slot ^ (row & 7);
    gld16(h2b + (size_t)(m0 + row) * H2_DIM + gslot * 8, (u16*)lsA + lin * 8);
  }
  __syncthreads();                      // single drain; rest is barrier-free

  f32x4 zero = {0.f, 0.f, 0.f, 0.f};

  for (int chunk = 0; chunk < 4; ++chunk) {
    const int p = pg * 8 + chunk * 2 + hs;

    f32x4 acc[4][4];
#pragma unroll
    for (int m = 0; m < 4; ++m)
#pragma unroll
      for (int n = 0; n < 4; ++n) acc[m][n] = zero;

#pragma unroll
    for (int kt = 0; kt < 8; ++kt) {
      Frag bfr[4];
#pragma unroll
      for (int nf = 0; nf < 4; ++nf)
        bfr[nf].s = *(const short8*)(W3f + (((size_t)(p * 4 + nf) * 8 + kt) * 64 + lane) * 8);
      Frag afr[4];
#pragma unroll
      for (int mf = 0; mf < 4; ++mf) {
        int row = mh * 64 + mf * 16 + c15;
        int g = kt * 4 + j4;
        int phys = g ^ (row & 7);
        afr[mf].s = *(const short8*)&lsA[row * 256 + phys * 8];
      }
#pragma unroll
      for (int mf = 0; mf < 4; ++mf)
#pragma unroll
        for (int nf = 0; nf < 4; ++nf)
          acc[mf][nf] = __builtin_amdgcn_mfma_f32_16x16x32_bf16(afr[mf].s, bfr[nf].s, acc[mf][nf], 0, 0, 0);
    }

    float w4v[4], b3v[4];
#pragma unroll
    for (int nf = 0; nf < 4; ++nf) {
      w4v[nf] = W4[p * A_DIM + nf * 16 + c15];
      b3v[nf] = b3[p * A_DIM + nf * 16 + c15];
    }
    const float b4v = b4[p];

    float s[4][4];
#pragma unroll
    for (int mf = 0; mf < 4; ++mf)
#pragma unroll
      for (int r = 0; r < 4; ++r) s[mf][r] = 0.f;
#pragma unroll
    for (int mf = 0; mf < 4; ++mf)
#pragma unroll
      for (int nf = 0; nf < 4; ++nf)
#pragma unroll
        for (int r = 0; r < 4; ++r) {
          float v = fmaxf(acc[mf][nf][r] + b3v[nf], 0.f);
          s[mf][r] += v * w4v[nf];
        }
#pragma unroll
    for (int mf = 0; mf < 4; ++mf)
#pragma unroll
      for (int r = 0; r < 4; ++r) {
        float v = s[mf][r];
        v += __shfl_xor(v, 1);
        v += __shfl_xor(v, 2);
        v += __shfl_xor(v, 4);
        v += __shfl_xor(v, 8);
        s[mf][r] = v;
      }
    if (c15 == 0) {
#pragma unroll
      for (int mf = 0; mf < 4; ++mf)
#pragma unroll
        for (int r = 0; r < 4; ++r) {
          int row = m0 + mh * 64 + mf * 16 + j4 * 4 + r;
          out[(size_t)row * P_DIM + p] = s[mf][r] + b4v;
        }
    }
  }
}

extern "C" void kernel_launch(void* const* d_in, const int* in_sizes, int n_in,
                              void* d_out, int out_size, void* d_ws, size_t ws_size,
                              hipStream_t stream) {
  const float* x  = (const float*)d_in[0];
  const float* W1 = (const float*)d_in[1];
  const float* b1 = (const float*)d_in[2];
  const float* W2 = (const float*)d_in[3];
  const float* b2 = (const float*)d_in[4];
  const float* W3 = (const float*)d_in[5];
  const float* b3 = (const float*)d_in[6];
  const float* W4 = (const float*)d_in[7];
  const float* b4 = (const float*)d_in[8];
  float* out = (float*)d_out;

  char* ws = (char*)d_ws;
  u16*   W1f  = (u16*)(ws);                    // 20,480,000 B (fragment-linear)
  u16*   W2b  = (u16*)(ws + 20480000);         //    262,144 B
  u16*   W3f  = (u16*)(ws + 20742144);         //  4,194,304 B (fragment-linear)
  u16*   h1b  = (u16*)(ws + 24936448);         //  8,388,608 B
  u16*   h2b  = (u16*)(ws + 33325056);         //  4,194,304 B
  float* part = (float*)(ws + 37519360);       // 8 x 16 MB = 134,217,728 B (end ~172 MB)

  k_convert_w1frag<<<dim3((1280000 + 255) / 256), dim3(256), 0, stream>>>(W1, W1f);
  k_convert<<<dim3(131072 / 4 / 256), dim3(256), 0, stream>>>(W2, W2b, 131072 / 4);
  k_convert_w3frag<<<dim3(262144 / 256), dim3(256), 0, stream>>>(W3, W3f);

  k_gemm1<<<dim3(128 * SPLITK), dim3(512), 0, stream>>>(x, W1f, part);
  k_reduce1<<<dim3(B_DIM * H1_DIM / 4 / 256), dim3(256), 0, stream>>>(part, b1, h1b);
  k_gemm2<<<dim3(64, 4), dim3(256), 0, stream>>>(h1b, W2b, b2, h2b);
  k_heads<<<dim3(1024), dim3(256), 0, stream>>>(h2b, W3f, b3, W4, b4, out);
}

// Round 14
// 320.348 us; speedup vs baseline: 1.4214x; 1.0914x over previous
//
#include <hip/hip_runtime.h>
#include <hip/hip_bf16.h>
#include <stdint.h>

typedef unsigned short u16;
typedef __attribute__((ext_vector_type(8))) short short8;
typedef __attribute__((ext_vector_type(8))) u16   u16x8;
typedef __attribute__((ext_vector_type(4))) u16   u16x4;
typedef __attribute__((ext_vector_type(4))) float f32x4;

#define B_DIM  8192
#define G_DIM  20000
#define H1_DIM 512
#define H2_DIM 256
#define P_DIM  128
#define A_DIM  64
#define SPLITK 8
#define NKT_ALL 625   // 20000 / 32

union Frag { short8 s; u16x8 u; };

__device__ __forceinline__ u16 f2b(float f) {
  union { __hip_bfloat16 b; u16 u; } c;
  c.b = __float2bfloat16(f);
  return c.u;
}
__device__ __forceinline__ float b2f(u16 u) {
  uint32_t x = ((uint32_t)u) << 16;
  return __uint_as_float(x);
}

__device__ __forceinline__ void gld16(const void* g, void* l) {
  __builtin_amdgcn_global_load_lds(
      (const __attribute__((address_space(1))) void*)g,
      (__attribute__((address_space(3))) void*)l, 16, 0, 0);
}

// ---------------- prep: f32 -> bf16 convert (vectorized) ----------------
__global__ void k_convert(const float* __restrict__ src, u16* __restrict__ dst, int n4) {
  int i = blockIdx.x * 256 + threadIdx.x;
  if (i >= n4) return;
  f32x4 v = ((const f32x4*)src)[i];
  u16x4 o;
  o[0] = f2b(v[0]); o[1] = f2b(v[1]);
  o[2] = f2b(v[2]); o[3] = f2b(v[3]);
  ((u16x4*)dst)[i] = o;
}

// ---------------- prep: W1 f32 -> MFMA-fragment-linear bf16 ----------------
// chunk ot = (rowblk*625 + kt)*64 + lane  ->  W1[rowblk*16 + (lane&15)]
//                                             [kt*32 + (lane>>4)*8 + 0..7]
__global__ void k_convert_w1frag(const float* __restrict__ W1, u16* __restrict__ W1f) {
  int ot = blockIdx.x * 256 + threadIdx.x;       // 0 .. 1,279,999
  if (ot >= (H1_DIM / 16) * NKT_ALL * 64) return;
  int rowblk = ot / (NKT_ALL * 64);
  int rem    = ot - rowblk * (NKT_ALL * 64);
  int kt     = rem >> 6;
  int lane   = rem & 63;
  int row = rowblk * 16 + (lane & 15);
  int col = kt * 32 + (lane >> 4) * 8;
  const float* src = W1 + (size_t)row * G_DIM + col;
  f32x4 v0 = *(const f32x4*)src;
  f32x4 v1 = *(const f32x4*)(src + 4);
  u16x8 o;
#pragma unroll
  for (int i = 0; i < 4; ++i) { o[i] = f2b(v0[i]); o[i + 4] = f2b(v1[i]); }
  ((u16x8*)W1f)[ot] = o;
}

// ---------------- prep: W3 f32 -> MFMA-fragment-linear bf16 ----------------
// chunk ot = ((p*4 + nf)*8 + kt)*64 + lane
//   element j = W3[p][h = kt*32 + (lane>>4)*8 + j][a = nf*16 + (lane&15)]
__global__ void k_convert_w3frag(const float* __restrict__ W3, u16* __restrict__ W3f) {
  int ot = blockIdx.x * 256 + threadIdx.x;       // 0 .. 262,143
  if (ot >= P_DIM * 4 * 8 * 64) return;
  int p    = ot >> 11;
  int rem  = ot & 2047;
  int nf   = rem >> 9;
  int kt   = (rem >> 6) & 7;
  int lane = ot & 63;
  int a  = nf * 16 + (lane & 15);
  int h0 = kt * 32 + (lane >> 4) * 8;
  u16x8 o;
#pragma unroll
  for (int j = 0; j < 8; ++j)
    o[j] = f2b(W3[((size_t)p * H2_DIM + h0 + j) * A_DIM + a]);
  ((u16x8*)W3f)[ot] = o;
}

// ---------------- K1: layer-1 GEMM (R14: BM=128, halved B-traffic) ----------------
// BM=128, BN=512, BK=64 supers. 512 thr / 8 waves; wave = 128(M) x 64(N),
// acc[8][4] = 128 VGPR; __launch_bounds__(512,2) -> cap 256, no spill.
// B-traffic halves vs BM=64 (2.6 -> 1.3 GB; R12 measured ~30us/GB marginal).
// B reg-direct from fragment-linear W1f (ks=blockIdx&7 XCD-pins 2.56MB slice).
// A staged via 128x64 f32->bf16 LDS tile (32 KB dbuf). Partials in bf16.
__global__ __launch_bounds__(512, 2)
void k_gemm1(const float* __restrict__ X, const u16* __restrict__ W1f,
             u16* __restrict__ partial) {
  const int ks = blockIdx.x & 7;
  const int m0 = (blockIdx.x >> 3) * 128;              // 64 m-blocks
  const int kt_begin = (ks == 0) ? 0 : (ks * 78 + 1);  // {79, 78x7} of 625
  const int nkt = (ks == 0) ? 79 : 78;

  const int tid  = threadIdx.x;
  const int lane = tid & 63;
  const int w    = tid >> 6;            // wave 0..7 -> N cols w*64..
  const int c15 = lane & 15, j4 = lane >> 4;
  const int w4 = w * 4;

  __shared__ u16 lsA[2][128 * 64];      // 16 KB/buf: 128 rows x 128B (8 slots of 16B)
                                        // phys slot = slot ^ (row&7)

  // A staging: thread -> row tid>>2 (0..127), col-granule cg=tid&3 (16 f32)
  const int aRow = tid >> 2;
  const int aCg  = tid & 3;
  const int aS0 = ((2 * aCg)     ^ (aRow & 7)) * 8;    // u16 offset of slot 0
  const int aS1 = ((2 * aCg + 1) ^ (aRow & 7)) * 8;
  const float* aSrc0 = X + (size_t)(m0 + aRow) * G_DIM + aCg * 16;

  f32x4 zero = {0.f, 0.f, 0.f, 0.f};
  f32x4 acc[8][4];
#pragma unroll
  for (int m = 0; m < 8; ++m)
#pragma unroll
    for (int n = 0; n < 4; ++n) acc[m][n] = zero;

  auto loadB = [&](int kt, Frag* br) {
#pragma unroll
    for (int n = 0; n < 4; ++n)
      br[n].s = *(const short8*)(W1f + ((size_t)((w4 + n) * NKT_ALL + kt) * 64 + lane) * 8);
  };
  f32x4 ar[4];                          // 16 f32 per thread (one 64-col super row-chunk)
  auto loadA = [&](int kt) {
    const float* src = aSrc0 + (size_t)kt * 32;
    ar[0] = *(const f32x4*)src;
    ar[1] = *(const f32x4*)(src + 4);
    ar[2] = *(const f32x4*)(src + 8);
    ar[3] = *(const f32x4*)(src + 12);
  };
  auto writeA = [&](int buf) {
    u16x8 o0, o1;
#pragma unroll
    for (int i = 0; i < 4; ++i) {
      o0[i] = f2b(ar[0][i]); o0[i + 4] = f2b(ar[1][i]);
      o1[i] = f2b(ar[2][i]); o1[i + 4] = f2b(ar[3][i]);
    }
    *(u16x8*)&lsA[buf][aRow * 64 + aS0] = o0;
    *(u16x8*)&lsA[buf][aRow * 64 + aS1] = o1;
  };
  auto readAfr = [&](int buf, int half, Frag* afr) {
#pragma unroll
    for (int m = 0; m < 8; ++m) {
      int row = m * 16 + c15;
      int g = half * 4 + j4;
      int phys = g ^ (row & 7);
      afr[m].s = *(const short8*)&lsA[buf][row * 64 + phys * 8];
    }
  };

  Frag bfrE[4], bfrO[4];

  // ---- prologue: A tile 0 (kt 0,1) -> LDS buf0; B(kt0) -> regs ----
  loadA(kt_begin);
  loadB(kt_begin, bfrE);
  writeA(0);
  asm volatile("s_waitcnt lgkmcnt(0)" ::: "memory");
  __builtin_amdgcn_s_barrier();
  __builtin_amdgcn_sched_barrier(0);

  const int nsuper = 39;                // covers kt 0..77 of the slice
  for (int T = 0; T < nsuper; ++T) {
    const int buf = T & 1;
    const int kt0 = kt_begin + 2 * T;
    const int ktN = 2 * (T + 1);
    const int ktNext = kt_begin + ((ktN < nkt) ? ktN : (nkt - 1));

    loadA(ktNext);                      // A tile T+1 (cover: whole body)
    loadB(kt0 + 1, bfrO);               // B kt1 (cover: 32 MFMA)

    Frag afr[8];
    readAfr(buf, 0, afr);
#pragma unroll
    for (int m = 0; m < 8; ++m)
#pragma unroll
      for (int n = 0; n < 4; ++n)
        acc[m][n] = __builtin_amdgcn_mfma_f32_16x16x32_bf16(afr[m].s, bfrE[n].s, acc[m][n], 0, 0, 0);

    loadB(ktNext, bfrE);                // next super's kt0 (crosses barrier in regs)

    readAfr(buf, 1, afr);
#pragma unroll
    for (int m = 0; m < 8; ++m)
#pragma unroll
      for (int n = 0; n < 4; ++n)
        acc[m][n] = __builtin_amdgcn_mfma_f32_16x16x32_bf16(afr[m].s, bfrO[n].s, acc[m][n], 0, 0, 0);

    writeA(buf ^ 1);                    // A tile T+1 (loads are body-old)
    asm volatile("s_waitcnt lgkmcnt(0)" ::: "memory");
    __builtin_amdgcn_s_barrier();
    __builtin_amdgcn_sched_barrier(0);
  }

  if (nkt == 79) {                      // ks==0 epilogue: kt 78 (in buf1, half 0)
    Frag afr[8];
    readAfr(1, 0, afr);
#pragma unroll
    for (int m = 0; m < 8; ++m)
#pragma unroll
      for (int n = 0; n < 4; ++n)
        acc[m][n] = __builtin_amdgcn_mfma_f32_16x16x32_bf16(afr[m].s, bfrE[n].s, acc[m][n], 0, 0, 0);
  }

  u16* outp = partial + ((size_t)ks * B_DIM + m0) * H1_DIM;
#pragma unroll
  for (int m = 0; m < 8; ++m)
#pragma unroll
    for (int n = 0; n < 4; ++n)
#pragma unroll
      for (int r = 0; r < 4; ++r) {
        int row = m * 16 + j4 * 4 + r;
        int col = w * 64 + n * 16 + c15;
        outp[(size_t)row * H1_DIM + col] = f2b(acc[m][n][r]);
      }
}

// ---------------- K1b: sum 8 bf16 partials + bias + relu -> h1 bf16 ----------------
__global__ void k_reduce1(const u16* __restrict__ partial, const float* __restrict__ b1,
                          u16* __restrict__ h1b) {
  const int n8 = B_DIM * H1_DIM / 8;
  int i = blockIdx.x * 256 + threadIdx.x;
  if (i >= n8) return;
  float s[8] = {0.f, 0.f, 0.f, 0.f, 0.f, 0.f, 0.f, 0.f};
#pragma unroll
  for (int k = 0; k < SPLITK; ++k) {
    u16x8 v = ((const u16x8*)partial)[(size_t)k * n8 + i];
#pragma unroll
    for (int j = 0; j < 8; ++j) s[j] += b2f(v[j]);
  }
  const int cb = i & (H1_DIM / 8 - 1);          // col block (8 cols)
  f32x4 bb0 = ((const f32x4*)b1)[cb * 2];
  f32x4 bb1 = ((const f32x4*)b1)[cb * 2 + 1];
  u16x8 o;
#pragma unroll
  for (int j = 0; j < 4; ++j) {
    o[j]     = f2b(fmaxf(s[j] + bb0[j], 0.f));
    o[j + 4] = f2b(fmaxf(s[j + 4] + bb1[j], 0.f));
  }
  ((u16x8*)h1b)[i] = o;
}

// ---------------- K2: layer-2 GEMM bf16, bias+relu fused -> h2 bf16 ----------------
__global__ __launch_bounds__(256, 2)
void k_gemm2(const u16* __restrict__ h1b, const u16* __restrict__ W2b,
             const float* __restrict__ b2, u16* __restrict__ h2b) {
  const int m0 = blockIdx.x * 128;
  const int n0 = blockIdx.y * 64;
  const int tid  = threadIdx.x;
  const int lane = tid & 63;
  const int wid  = tid >> 6;
  const int wr = wid >> 1, wc = wid & 1;
  const int c15 = lane & 15, j4 = lane >> 4;

  __shared__ u16 lsA[2][128 * 32];
  __shared__ u16 lsB[2][64 * 32];

  f32x4 zero = {0.f, 0.f, 0.f, 0.f};
  f32x4 acc[4][2];
#pragma unroll
  for (int m = 0; m < 4; ++m) { acc[m][0] = zero; acc[m][1] = zero; }

  auto stage = [&](int buf, int kt) {
    const int k0 = kt * 32;
#pragma unroll
    for (int c = 0; c < 2; ++c) {
      int lin = c * 256 + tid;
      int row = lin >> 2, slot = lin & 3;
      int gslot = slot ^ ((row >> 1) & 3);
      gld16(h1b + (size_t)(m0 + row) * H1_DIM + k0 + gslot * 8, &lsA[buf][lin * 8]);
    }
    {
      int lin = tid;
      int row = lin >> 2, slot = lin & 3;
      int gslot = slot ^ ((row >> 1) & 3);
      gld16(W2b + (size_t)(n0 + row) * H1_DIM + k0 + gslot * 8, &lsB[buf][lin * 8]);
    }
  };

  stage(0, 0);
  __syncthreads();
  int buf = 0;
  const int nkt = H1_DIM / 32;   // 16
  for (int t = 0; t < nkt; ++t) {
    if (t + 1 < nkt) stage(buf ^ 1, t + 1);
    Frag bfr[2];
#pragma unroll
    for (int n = 0; n < 2; ++n) {
      int row = wc * 32 + n * 16 + c15;
      int slot = j4 ^ ((row >> 1) & 3);
      bfr[n].s = *(const short8*)&lsB[buf][row * 32 + slot * 8];
    }
    Frag afr[4];
#pragma unroll
    for (int m = 0; m < 4; ++m) {
      int row = wr * 64 + m * 16 + c15;
      int slot = j4 ^ ((row >> 1) & 3);
      afr[m].s = *(const short8*)&lsA[buf][row * 32 + slot * 8];
    }
#pragma unroll
    for (int m = 0; m < 4; ++m)
#pragma unroll
      for (int n = 0; n < 2; ++n)
        acc[m][n] = __builtin_amdgcn_mfma_f32_16x16x32_bf16(afr[m].s, bfr[n].s, acc[m][n], 0, 0, 0);
    __syncthreads();
    buf ^= 1;
  }

  float b2v[2];
  b2v[0] = b2[n0 + wc * 32 + c15];
  b2v[1] = b2[n0 + wc * 32 + 16 + c15];
#pragma unroll
  for (int m = 0; m < 4; ++m)
#pragma unroll
    for (int n = 0; n < 2; ++n)
#pragma unroll
      for (int r = 0; r < 4; ++r) {
        int row = m0 + wr * 64 + m * 16 + j4 * 4 + r;
        int col = n0 + wc * 32 + n * 16 + c15;
        h2b[(size_t)row * H2_DIM + col] = f2b(fmaxf(acc[m][n][r] + b2v[n], 0.f));
      }
}

// ---------------- K3: fused heads (R13 version — kept) ----------------
__global__ __launch_bounds__(256, 2)
void k_heads(const u16* __restrict__ h2b, const u16* __restrict__ W3f,
             const float* __restrict__ b3, const float* __restrict__ W4,
             const float* __restrict__ b4, float* __restrict__ out) {
  const int pg = blockIdx.x & 15;       // p-group (8 heads)
  const int mb = blockIdx.x >> 4;       // m-block (128 rows)
  const int m0 = mb * 128;

  const int tid  = threadIdx.x;
  const int lane = tid & 63;
  const int w    = tid >> 6;
  const int mh = w & 1;                 // 64-row half
  const int hs = w >> 1;                // head slot 0/1
  const int c15 = lane & 15, j4 = lane >> 4;

  __shared__ u16 lsA[128 * 256];        // 64 KB; row=512B=32 slots; phys = slot ^ (row&7)

#pragma unroll
  for (int c = 0; c < 16; ++c) {
    int lin = c * 256 + tid;
    int row = lin >> 5, slot = lin & 31;
    int gslot = slot ^ (row & 7);
    gld16(h2b + (size_t)(m0 + row) * H2_DIM + gslot * 8, (u16*)lsA + lin * 8);
  }
  __syncthreads();

  f32x4 zero = {0.f, 0.f, 0.f, 0.f};

  for (int chunk = 0; chunk < 4; ++chunk) {
    const int p = pg * 8 + chunk * 2 + hs;

    f32x4 acc[4][4];
#pragma unroll
    for (int m = 0; m < 4; ++m)
#pragma unroll
      for (int n = 0; n < 4; ++n) acc[m][n] = zero;

#pragma unroll
    for (int kt = 0; kt < 8; ++kt) {
      Frag bfr[4];
#pragma unroll
      for (int nf = 0; nf < 4; ++nf)
        bfr[nf].s = *(const short8*)(W3f + (((size_t)(p * 4 + nf) * 8 + kt) * 64 + lane) * 8);
      Frag afr[4];
#pragma unroll
      for (int mf = 0; mf < 4; ++mf) {
        int row = mh * 64 + mf * 16 + c15;
        int g = kt * 4 + j4;
        int phys = g ^ (row & 7);
        afr[mf].s = *(const short8*)&lsA[row * 256 + phys * 8];
      }
#pragma unroll
      for (int mf = 0; mf < 4; ++mf)
#pragma unroll
        for (int nf = 0; nf < 4; ++nf)
          acc[mf][nf] = __builtin_amdgcn_mfma_f32_16x16x32_bf16(afr[mf].s, bfr[nf].s, acc[mf][nf], 0, 0, 0);
    }

    float w4v[4], b3v[4];
#pragma unroll
    for (int nf = 0; nf < 4; ++nf) {
      w4v[nf] = W4[p * A_DIM + nf * 16 + c15];
      b3v[nf] = b3[p * A_DIM + nf * 16 + c15];
    }
    const float b4v = b4[p];

    float s[4][4];
#pragma unroll
    for (int mf = 0; mf < 4; ++mf)
#pragma unroll
      for (int r = 0; r < 4; ++r) s[mf][r] = 0.f;
#pragma unroll
    for (int mf = 0; mf < 4; ++mf)
#pragma unroll
      for (int nf = 0; nf < 4; ++nf)
#pragma unroll
        for (int r = 0; r < 4; ++r) {
          float v = fmaxf(acc[mf][nf][r] + b3v[nf], 0.f);
          s[mf][r] += v * w4v[nf];
        }
#pragma unroll
    for (int mf = 0; mf < 4; ++mf)
#pragma unroll
      for (int r = 0; r < 4; ++r) {
        float v = s[mf][r];
        v += __shfl_xor(v, 1);
        v += __shfl_xor(v, 2);
        v += __shfl_xor(v, 4);
        v += __shfl_xor(v, 8);
        s[mf][r] = v;
      }
    if (c15 == 0) {
#pragma unroll
      for (int mf = 0; mf < 4; ++mf)
#pragma unroll
        for (int r = 0; r < 4; ++r) {
          int row = m0 + mh * 64 + mf * 16 + j4 * 4 + r;
          out[(size_t)row * P_DIM + p] = s[mf][r] + b4v;
        }
    }
  }
}

extern "C" void kernel_launch(void* const* d_in, const int* in_sizes, int n_in,
                              void* d_out, int out_size, void* d_ws, size_t ws_size,
                              hipStream_t stream) {
  const float* x  = (const float*)d_in[0];
  const float* W1 = (const float*)d_in[1];
  const float* b1 = (const float*)d_in[2];
  const float* W2 = (const float*)d_in[3];
  const float* b2 = (const float*)d_in[4];
  const float* W3 = (const float*)d_in[5];
  const float* b3 = (const float*)d_in[6];
  const float* W4 = (const float*)d_in[7];
  const float* b4 = (const float*)d_in[8];
  float* out = (float*)d_out;

  char* ws = (char*)d_ws;
  u16*   W1f  = (u16*)(ws);                    // 20,480,000 B (fragment-linear)
  u16*   W2b  = (u16*)(ws + 20480000);         //    262,144 B
  u16*   W3f  = (u16*)(ws + 20742144);         //  4,194,304 B (fragment-linear)
  u16*   h1b  = (u16*)(ws + 24936448);         //  8,388,608 B
  u16*   h2b  = (u16*)(ws + 33325056);         //  4,194,304 B
  u16*   part = (u16*)(ws + 37519360);         // 8 x 8 MB = 67,108,864 B (end ~105 MB)

  k_convert_w1frag<<<dim3((1280000 + 255) / 256), dim3(256), 0, stream>>>(W1, W1f);
  k_convert<<<dim3(131072 / 4 / 256), dim3(256), 0, stream>>>(W2, W2b, 131072 / 4);
  k_convert_w3frag<<<dim3(262144 / 256), dim3(256), 0, stream>>>(W3, W3f);

  k_gemm1<<<dim3(64 * SPLITK), dim3(512), 0, stream>>>(x, W1f, part);
  k_reduce1<<<dim3(B_DIM * H1_DIM / 8 / 256), dim3(256), 0, stream>>>(part, b1, h1b);
  k_gemm2<<<dim3(64, 4), dim3(256), 0, stream>>>(h1b, W2b, b2, h2b);
  k_heads<<<dim3(1024), dim3(256), 0, stream>>>(h2b, W3f, b3, W4, b4, out);
}